// Round 8
// baseline (374.265 us; speedup 1.0000x reference)
//
#include <hip/hip_runtime.h>

#define N_NODES  80000
#define N_EDGES  1280000
#define N_GRAPHS 512
#define DIM      64
#define NCLS     10

#define ETILE    2048
#define NTILE    625      // N_EDGES / ETILE exactly
#define NSCB     313      // ceil(80000/256) scan blocks

typedef _Float16 half8f __attribute__((ext_vector_type(8)));  // 8 f16 (4 VGPRs)
typedef float float4f __attribute__((ext_vector_type(4)));    // 4 fp32 acc

static __device__ __forceinline__ unsigned short f2h(float f) {
    _Float16 h = (_Float16)f;                 // v_cvt_f16_f32, RNE
    return __builtin_bit_cast(unsigned short, h);
}
static __device__ __forceinline__ float h_lo(unsigned v) {
    return (float)__builtin_bit_cast(_Float16, (unsigned short)(v & 0xFFFF));
}
static __device__ __forceinline__ float h_hi(unsigned v) {
    return (float)__builtin_bit_cast(_Float16, (unsigned short)(v >> 16));
}

// ---------- Pass A (merged): blocks [0,5000) cast x->f16; [5000,5064) pack
// W1/W2 MFMA frags; [5064, 5064+NTILE) node-degree histogram (global atomics).
__global__ __launch_bounds__(256) void k_prepdeg(const int* __restrict__ ei,
        const float* __restrict__ x,
        const float* __restrict__ wr1, const float* __restrict__ wo1,
        const float* __restrict__ wr2, const float* __restrict__ wo2,
        int* __restrict__ deg, unsigned short* __restrict__ xb,
        unsigned short* __restrict__ wf) {
    int bid = blockIdx.x, t = threadIdx.x;
    if (bid < 5000) {
        int i = bid * 256 + t;                  // N_NODES*16 float4s
        float4 v = ((const float4*)x)[i];
        ushort4 o;
        o.x = f2h(v.x); o.y = f2h(v.y); o.z = f2h(v.z); o.w = f2h(v.w);
        ((ushort4*)xb)[i] = o;
    } else if (bid < 5064) {
        int idx = (bid - 5000) * 256 + t;       // < 2*8192
        int j = idx & 7, lane = (idx >> 3) & 63;
        int ks = (idx >> 9) & 3, nt = (idx >> 11) & 3, l = idx >> 13;
        int k = ks * 32 + ((lane >> 4) & 3) * 8 + j;
        int n = nt * 16 + (lane & 15);
        const float* wr = (l == 0) ? wr1 : wr2;
        const float* wo = (l == 0) ? wo1 : wo2;
        float val = (k < 64) ? wr[n * 64 + k] : wo[n * 64 + (k - 64)];
        wf[idx] = f2h(val);
    } else {
        int tile = bid - 5064;
        int base = tile * ETILE;
        int end = base + ETILE;
        for (int i = base + t; i < end; i += 256)
            atomicAdd(&deg[ei[N_EDGES + i]], 1);
    }
}

// ---------- Scan 1: per-256-node block sums of deg
__global__ __launch_bounds__(256) void k_bsum(const int* __restrict__ deg,
        int* __restrict__ bsum) {
    __shared__ int sa[256];
    int b = blockIdx.x, t = threadIdx.x;
    int idx = b * 256 + t;
    sa[t] = (idx < N_NODES) ? deg[idx] : 0;
    __syncthreads();
    for (int off = 128; off > 0; off >>= 1) {
        if (t < off) sa[t] += sa[t + off];
        __syncthreads();
    }
    if (t == 0) bsum[b] = sa[0];
}

// ---------- Scan 2: one-block exclusive scan of NSCB block sums
__global__ __launch_bounds__(256) void k_btop(const int* __restrict__ bsum,
        int* __restrict__ bbase) {
    __shared__ int sa[256], sb[256];
    int t = threadIdx.x;
    int l0 = (2 * t     < NSCB) ? bsum[2 * t]     : 0;
    int l1 = (2 * t + 1 < NSCB) ? bsum[2 * t + 1] : 0;
    int s = l0 + l1;
    sa[t] = s; __syncthreads();
    int* sp = sa; int* dp = sb;
    for (int off = 1; off < 256; off <<= 1) {
        dp[t] = sp[t] + ((t >= off) ? sp[t - off] : 0);
        __syncthreads();
        int* tmp = sp; sp = dp; dp = tmp;
    }
    int ex = sp[t] - s;
    if (2 * t     < NSCB) bbase[2 * t]     = ex;
    if (2 * t + 1 < NSCB) bbase[2 * t + 1] = ex + l0;
}

// ---------- Scan 3: expand to node-level rowptr + working copy cur
__global__ __launch_bounds__(256) void k_expand(const int* __restrict__ deg,
        const int* __restrict__ bbase, int* __restrict__ rowptr,
        int* __restrict__ cur) {
    __shared__ int sa[256], sb[256];
    int b = blockIdx.x, t = threadIdx.x;
    int idx = b * 256 + t;
    int v = (idx < N_NODES) ? deg[idx] : 0;
    sa[t] = v; __syncthreads();
    int* sp = sa; int* dp = sb;
    for (int off = 1; off < 256; off <<= 1) {
        dp[t] = sp[t] + ((t >= off) ? sp[t - off] : 0);
        __syncthreads();
        int* tmp = sp; sp = dp; dp = tmp;
    }
    if (idx < N_NODES) {
        int rb = bbase[b] + sp[t] - v;
        rowptr[idx] = rb;
        cur[idx] = rb;
    }
    if (b == 0 && t == 0) rowptr[N_NODES] = N_EDGES;
}

// ---------- Scatter: col[p] = src, p from per-node global atomic cursor.
// Order within a node nondeterministic (f16 sum-order perturbation only).
__global__ __launch_bounds__(256) void k_scatter3(const int* __restrict__ ei,
        int* __restrict__ cur, int* __restrict__ col) {
    int tile = blockIdx.x, t = threadIdx.x;
    int base = tile * ETILE;
    int end = base + ETILE;
    for (int i = base + t; i < end; i += 256) {
        int s = ei[i], d = ei[N_EDGES + i];
        int p = atomicAdd(&cur[d], 1);
        col[p] = s;
    }
}

// ---------- fused gather + MFMA linear: block = 64 nodes, wave = 16 nodes.
// Phase 1: gather (8 edge slots x 8 f16x8 chunks per lane), packed f16
// accumulate, rows parked in padded LDS. Phase 2: MFMA epilogue (f16).
// Wave-private LDS rows -> no barrier needed.  [round-4 proven, unchanged]
__global__ __launch_bounds__(256) void k_gatherlin(
        const unsigned short* __restrict__ Xin,
        const int* __restrict__ rowptr, const int* __restrict__ col,
        const unsigned short* __restrict__ wf, const float* __restrict__ bias,
        unsigned short* __restrict__ out, int relu) {
    __shared__ uint4 sAgg[64][9];
    const half8f* Xq = (const half8f*)Xin;
    int t = threadIdx.x, w = t >> 6, lane = t & 63;
    int e = lane >> 3, c = lane & 7;
    int nb = blockIdx.x * 64 + w * 16;          // first node of this wave
    int rp = (lane <= 16) ? rowptr[nb + lane] : 0;
    for (int n = 0; n < 16; ++n) {
        int start = __shfl(rp, n), end = __shfl(rp, n + 1);
        half8f acc = {};
        int base = start;
        for (; base + 16 <= end; base += 16) {   // 2 16B loads in flight
            int i0 = col[base + e];
            int i1 = col[base + 8 + e];
            half8f v0 = Xq[(size_t)i0 * 8 + c];
            half8f v1 = Xq[(size_t)i1 * 8 + c];
            acc = acc + v0;
            acc = acc + v1;
        }
        for (; base + 8 <= end; base += 8) {
            int i0 = col[base + e];
            acc = acc + Xq[(size_t)i0 * 8 + c];
        }
        int r = end - base;
        if (e < r) {
            int i0 = col[base + e];
            acc = acc + Xq[(size_t)i0 * 8 + c];
        }
#pragma unroll
        for (int off = 8; off < 64; off <<= 1) {
            uint4 au = __builtin_bit_cast(uint4, acc);
            uint4 bu;
            bu.x = __shfl_xor(au.x, off); bu.y = __shfl_xor(au.y, off);
            bu.z = __shfl_xor(au.z, off); bu.w = __shfl_xor(au.w, off);
            acc = acc + __builtin_bit_cast(half8f, bu);
        }
        if (e == 0) sAgg[w * 16 + n][c] = __builtin_bit_cast(uint4, acc);
    }
    // phase 2: out = act([agg|x] @ W + b)  (wave-private rows; lgkmcnt only)
    int quad = lane >> 4, l15 = lane & 15;
    int m = nb + l15;
    half8f a0 = *(const half8f*)&sAgg[w * 16 + l15][quad];
    half8f a1 = *(const half8f*)&sAgg[w * 16 + l15][4 + quad];
    const half8f* xr = (const half8f*)(Xin + (size_t)m * 64);
    half8f a2 = xr[quad];
    half8f a3 = xr[4 + quad];
    int orow = nb + quad * 4;
#pragma unroll
    for (int nt = 0; nt < 4; ++nt) {
        const half8f* wp = (const half8f*)(wf + ((size_t)(nt * 4) * 64 + lane) * 8);
        half8f b0 = wp[0];
        half8f b1 = wp[64];
        half8f b2 = wp[128];
        half8f b3 = wp[192];
        float4f acc = {0.f, 0.f, 0.f, 0.f};
        acc = __builtin_amdgcn_mfma_f32_16x16x32_f16(a0, b0, acc, 0, 0, 0);
        acc = __builtin_amdgcn_mfma_f32_16x16x32_f16(a1, b1, acc, 0, 0, 0);
        acc = __builtin_amdgcn_mfma_f32_16x16x32_f16(a2, b2, acc, 0, 0, 0);
        acc = __builtin_amdgcn_mfma_f32_16x16x32_f16(a3, b3, acc, 0, 0, 0);
        float bi = bias[nt * 16 + l15];
#pragma unroll
        for (int r2 = 0; r2 < 4; ++r2) {
            float v = acc[r2] + bi;
            if (relu) v = fmaxf(v, 0.f);
            out[(size_t)(orow + r2) * 64 + nt * 16 + l15] = f2h(v);
        }
    }
}

static __device__ __forceinline__ int lowerb(const int* a, int n, int key) {
    int lo = 0, hi = n;
    while (lo < hi) { int mid = (lo + hi) >> 1; if (a[mid] < key) lo = mid + 1; else hi = mid; }
    return lo;
}

// ---------- layer-3 collapse, stage 1: per-graph partial sums, 4 parts/graph
// [round-4 proven, unchanged]
__global__ __launch_bounds__(256) void k_gsum(const unsigned short* __restrict__ h2,
        const int* __restrict__ rowptr, const int* __restrict__ col,
        const int* __restrict__ batch, float* __restrict__ S4) {
    __shared__ float red1[4][64];
    __shared__ float red2[4][64];
    const uint4* Xq = (const uint4*)h2;
    int g = blockIdx.x >> 2, part = blockIdx.x & 3;
    int t = threadIdx.x, w = t >> 6, lane = t & 63;
    int e = lane >> 3, c = lane & 7;
    int slot = w * 8 + e;                        // 32 edge slots
    int ns = lowerb(batch, N_NODES, g);
    int ne = lowerb(batch, N_NODES, g + 1);
    int a0 = ns + (int)(((long long)(ne - ns) * part) >> 2);
    int a1 = ns + (int)(((long long)(ne - ns) * (part + 1)) >> 2);
    int es = rowptr[a0], ee = rowptr[a1];
    float acc[8] = {0.f, 0.f, 0.f, 0.f, 0.f, 0.f, 0.f, 0.f};
    int idx = es + slot;
    for (; idx + 32 < ee; idx += 64) {           // 2 uint4 loads in flight
        int i0 = col[idx];
        int i1 = col[idx + 32];
        uint4 v0 = Xq[(size_t)i0 * 8 + c];
        uint4 v1 = Xq[(size_t)i1 * 8 + c];
        acc[0] += h_lo(v0.x) + h_lo(v1.x); acc[1] += h_hi(v0.x) + h_hi(v1.x);
        acc[2] += h_lo(v0.y) + h_lo(v1.y); acc[3] += h_hi(v0.y) + h_hi(v1.y);
        acc[4] += h_lo(v0.z) + h_lo(v1.z); acc[5] += h_hi(v0.z) + h_hi(v1.z);
        acc[6] += h_lo(v0.w) + h_lo(v1.w); acc[7] += h_hi(v0.w) + h_hi(v1.w);
    }
    if (idx < ee) {
        int i0 = col[idx];
        uint4 v0 = Xq[(size_t)i0 * 8 + c];
        acc[0] += h_lo(v0.x); acc[1] += h_hi(v0.x);
        acc[2] += h_lo(v0.y); acc[3] += h_hi(v0.y);
        acc[4] += h_lo(v0.z); acc[5] += h_hi(v0.z);
        acc[6] += h_lo(v0.w); acc[7] += h_hi(v0.w);
    }
    float acc2[8] = {0.f, 0.f, 0.f, 0.f, 0.f, 0.f, 0.f, 0.f};
    for (int i = a0 + slot; i < a1; i += 32) {   // node (root) sums
        uint4 v = Xq[(size_t)i * 8 + c];
        acc2[0] += h_lo(v.x); acc2[1] += h_hi(v.x);
        acc2[2] += h_lo(v.y); acc2[3] += h_hi(v.y);
        acc2[4] += h_lo(v.z); acc2[5] += h_hi(v.z);
        acc2[6] += h_lo(v.w); acc2[7] += h_hi(v.w);
    }
#pragma unroll
    for (int off = 8; off < 64; off <<= 1) {
#pragma unroll
        for (int j = 0; j < 8; ++j) {
            acc[j]  += __shfl_xor(acc[j],  off);
            acc2[j] += __shfl_xor(acc2[j], off);
        }
    }
    if (e == 0) {
#pragma unroll
        for (int j = 0; j < 8; ++j) {
            red1[w][c * 8 + j] = acc[j];
            red2[w][c * 8 + j] = acc2[j];
        }
    }
    __syncthreads();
    if (t < 64) {
        S4[(size_t)blockIdx.x * 128 + t] =
            red1[0][t] + red1[1][t] + red1[2][t] + red1[3][t];
    } else if (t < 128) {
        int d = t - 64;
        S4[(size_t)blockIdx.x * 128 + 64 + d] =
            red2[0][d] + red2[1][d] + red2[2][d] + red2[3][d];
    }
}

// ---------- layer-3 collapse, stage 2: pooled matmuls + head (all fp32)
__global__ __launch_bounds__(64) void k_head2(const float* __restrict__ S4,
        const int* __restrict__ batch,
        const float* __restrict__ wr3, const float* __restrict__ wo3,
        const float* __restrict__ b3,
        const float* __restrict__ wlin, const float* __restrict__ blin,
        float* __restrict__ out) {
    __shared__ float s1[64], s2[64], pl[64];
    int g = blockIdx.x, t = threadIdx.x;
    int ns = lowerb(batch, N_NODES, g);
    int ne = lowerb(batch, N_NODES, g + 1);
    float inv = 1.f / (float)((ne > ns) ? (ne - ns) : 1);
    const float* Sg = S4 + (size_t)g * 4 * 128;
    s1[t] = (Sg[t]       + Sg[128 + t]       + Sg[256 + t]       + Sg[384 + t]) * inv;
    s2[t] = (Sg[64 + t]  + Sg[192 + t]       + Sg[320 + t]       + Sg[448 + t]) * inv;
    __syncthreads();
    float acc = b3[t];
    for (int k = 0; k < 64; ++k)
        acc += s1[k] * wr3[t * 64 + k] + s2[k] * wo3[t * 64 + k];
    pl[t] = acc;
    __syncthreads();
    float myout = 0.f;
    for (int cls = 0; cls < NCLS; ++cls) {
        float vv = pl[t] * wlin[cls * 64 + t];
        for (int off = 32; off > 0; off >>= 1) vv += __shfl_xor(vv, off);
        if (t == cls) myout = vv + blin[cls];
    }
    if (t < NCLS) out[g * NCLS + t] = myout;
}

extern "C" void kernel_launch(void* const* d_in, const int* in_sizes, int n_in,
                              void* d_out, int out_size, void* d_ws, size_t ws_size,
                              hipStream_t stream) {
    const float* x     = (const float*)d_in[0];
    const int*   ei    = (const int*)d_in[1];
    const int*   batch = (const int*)d_in[2];
    const float* wr1 = (const float*)d_in[3];
    const float* b1  = (const float*)d_in[4];
    const float* wo1 = (const float*)d_in[5];
    const float* wr2 = (const float*)d_in[6];
    const float* b2  = (const float*)d_in[7];
    const float* wo2 = (const float*)d_in[8];
    const float* wr3 = (const float*)d_in[9];
    const float* b3  = (const float*)d_in[10];
    const float* wo3 = (const float*)d_in[11];
    const float* wlin = (const float*)d_in[12];
    const float* blin = (const float*)d_in[13];
    float* out = (float*)d_out;

    char* p = (char*)d_ws;
    auto alloc = [&](size_t bytes) { char* r = p; p += (bytes + 255) & ~(size_t)255; return r; };
    int*   deg     = (int*)alloc((size_t)N_NODES * sizeof(int));
    int*   bsum    = (int*)alloc(NSCB * sizeof(int));
    int*   bbase   = (int*)alloc(NSCB * sizeof(int));
    int*   rowptr  = (int*)alloc((N_NODES + 1) * sizeof(int));
    int*   cur     = (int*)alloc((size_t)N_NODES * sizeof(int));
    int*   col     = (int*)alloc((size_t)N_EDGES * sizeof(int));
    unsigned short* wf  = (unsigned short*)alloc(2 * 8192 * sizeof(unsigned short));
    unsigned short* xbf = (unsigned short*)alloc((size_t)N_NODES * 64 * 2);
    unsigned short* hA  = (unsigned short*)alloc((size_t)N_NODES * 64 * 2);
    unsigned short* hB  = (unsigned short*)alloc((size_t)N_NODES * 64 * 2);
    float* S4      = (float*)alloc((size_t)N_GRAPHS * 4 * 128 * sizeof(float));

    // CSR build: direct node-level (atomic histogram + 3 tiny scans + scatter)
    hipMemsetAsync(deg, 0, (size_t)N_NODES * sizeof(int), stream);
    k_prepdeg <<<5064 + NTILE, 256, 0, stream>>>(ei, x, wr1, wo1, wr2, wo2,
                                                 deg, xbf, wf);
    k_bsum    <<<NSCB,  256, 0, stream>>>(deg, bsum);
    k_btop    <<<1,     256, 0, stream>>>(bsum, bbase);
    k_expand  <<<NSCB,  256, 0, stream>>>(deg, bbase, rowptr, cur);
    k_scatter3<<<NTILE, 256, 0, stream>>>(ei, cur, col);

    // layers 1+2: fused gather+linear (round-4 proven)
    k_gatherlin<<<N_NODES / 64, 256, 0, stream>>>(xbf, rowptr, col, wf,        b1, hA, 1);
    k_gatherlin<<<N_NODES / 64, 256, 0, stream>>>(hA,  rowptr, col, wf + 8192, b2, hB, 1);

    // layer 3 + pool collapsed
    k_gsum <<<N_GRAPHS * 4, 256, 0, stream>>>(hB, rowptr, col, batch, S4);
    k_head2<<<N_GRAPHS,     64,  0, stream>>>(S4, batch, wr3, wo3, b3, wlin, blin, out);
}

// Round 9
// 253.949 us; speedup vs baseline: 1.4738x; 1.4738x over previous
//
#include <hip/hip_runtime.h>

#define N_NODES  80000
#define N_EDGES  1280000
#define N_GRAPHS 512
#define DIM      64
#define NCLS     10

#define ETILE    2048
#define NTILE    625      // N_EDGES / ETILE exactly
#define NCB      625      // 128-node buckets; 80000/128 = 625 exactly
#define BSH      7        // log2(128)
#define HPAD     640

typedef _Float16 half8f __attribute__((ext_vector_type(8)));  // 8 f16 (4 VGPRs)
typedef float float4f __attribute__((ext_vector_type(4)));    // 4 fp32 acc

static __device__ __forceinline__ unsigned short f2h(float f) {
    _Float16 h = (_Float16)f;                 // v_cvt_f16_f32, RNE
    return __builtin_bit_cast(unsigned short, h);
}
static __device__ __forceinline__ float h_lo(unsigned v) {
    return (float)__builtin_bit_cast(_Float16, (unsigned short)(v & 0xFFFF));
}
static __device__ __forceinline__ float h_hi(unsigned v) {
    return (float)__builtin_bit_cast(_Float16, (unsigned short)(v >> 16));
}

// ---------- Pass A (merged): blocks [0,NTILE) per-tile histogram over
// 128-node buckets; blocks [NTILE, NTILE+5000) cast x->f16; rest pack W1/W2.
__global__ __launch_bounds__(256) void k_histprep(const int* __restrict__ ei,
        const float* __restrict__ x,
        const float* __restrict__ wr1, const float* __restrict__ wo1,
        const float* __restrict__ wr2, const float* __restrict__ wo2,
        int* __restrict__ hmat, unsigned short* __restrict__ xb,
        unsigned short* __restrict__ wf) {
    __shared__ int hist[NCB];
    int bid = blockIdx.x, t = threadIdx.x;
    if (bid < NTILE) {
        int tile = bid;
        for (int i = t; i < NCB; i += 256) hist[i] = 0;
        __syncthreads();
        int base = tile * ETILE;
        int end = base + ETILE;
        for (int i = base + t; i < end; i += 256)
            atomicAdd(&hist[__builtin_nontemporal_load(ei + N_EDGES + i) >> BSH], 1);
        __syncthreads();
        for (int i = t; i < NCB; i += 256) hmat[tile * HPAD + i] = hist[i];
        return;
    }
    int pb = bid - NTILE;
    if (pb < 5000) {
        int i = pb * 256 + t;                   // N_NODES*16 float4s
        float4 v = ((const float4*)x)[i];
        ushort4 o;
        o.x = f2h(v.x); o.y = f2h(v.y); o.z = f2h(v.z); o.w = f2h(v.w);
        ((ushort4*)xb)[i] = o;
    } else {
        int idx = (pb - 5000) * 256 + t;        // < 2*8192
        int j = idx & 7, lane = (idx >> 3) & 63;
        int ks = (idx >> 9) & 3, nt = (idx >> 11) & 3, l = idx >> 13;
        int k = ks * 32 + ((lane >> 4) & 3) * 8 + j;
        int n = nt * 16 + (lane & 15);
        const float* wr = (l == 0) ? wr1 : wr2;
        const float* wo = (l == 0) ? wo1 : wo2;
        float val = (k < 64) ? wr[n * 64 + k] : wo[n * 64 + (k - 64)];
        wf[idx] = f2h(val);
    }
}

// ---------- Pass B1: per-bucket exclusive scan across 625 tiles (3 elems/thr)
__global__ __launch_bounds__(256) void k_scanT(const int* __restrict__ hmat,
        int* __restrict__ obase, int* __restrict__ btot) {
    __shared__ int sa[256], sb[256];
    int b = blockIdx.x, t = threadIdx.x;
    int j0 = 3 * t;
    int l0 = (j0     < NTILE) ? hmat[(j0    ) * HPAD + b] : 0;
    int l1 = (j0 + 1 < NTILE) ? hmat[(j0 + 1) * HPAD + b] : 0;
    int l2 = (j0 + 2 < NTILE) ? hmat[(j0 + 2) * HPAD + b] : 0;
    int s = l0 + l1 + l2;
    sa[t] = s; __syncthreads();
    int* sp = sa; int* dp = sb;
    for (int off = 1; off < 256; off <<= 1) {
        dp[t] = sp[t] + ((t >= off) ? sp[t - off] : 0);
        __syncthreads();
        int* tmp = sp; sp = dp; dp = tmp;
    }
    int ex = sp[t] - s;
    if (j0     < NTILE) obase[(j0    ) * HPAD + b] = ex;
    if (j0 + 1 < NTILE) obase[(j0 + 1) * HPAD + b] = ex + l0;
    if (j0 + 2 < NTILE) obase[(j0 + 2) * HPAD + b] = ex + l0 + l1;
    if (t == 255) btot[b] = sp[255];
}

// ---------- Pass B2: one-block scan of 625 bucket totals -> bucket bases
__global__ __launch_bounds__(256) void k_scanB(const int* __restrict__ btot,
        int* __restrict__ bucketbase) {
    __shared__ int sa[256], sb[256];
    int t = threadIdx.x;
    int b0 = t * 5;
    int v0 = (b0     < NCB) ? btot[b0]     : 0;
    int v1 = (b0 + 1 < NCB) ? btot[b0 + 1] : 0;
    int v2 = (b0 + 2 < NCB) ? btot[b0 + 2] : 0;
    int v3 = (b0 + 3 < NCB) ? btot[b0 + 3] : 0;
    int v4 = (b0 + 4 < NCB) ? btot[b0 + 4] : 0;
    int s = v0 + v1 + v2 + v3 + v4;
    sa[t] = s; __syncthreads();
    int* sp = sa; int* dp = sb;
    for (int off = 1; off < 256; off <<= 1) {
        dp[t] = sp[t] + ((t >= off) ? sp[t - off] : 0);
        __syncthreads();
        int* tmp = sp; sp = dp; dp = tmp;
    }
    int ex = sp[t] - s;
    if (b0     < NCB) bucketbase[b0]     = ex;
    if (b0 + 1 < NCB) bucketbase[b0 + 1] = ex + v0;
    if (b0 + 2 < NCB) bucketbase[b0 + 2] = ex + v0 + v1;
    if (b0 + 3 < NCB) bucketbase[b0 + 3] = ex + v0 + v1 + v2;
    if (b0 + 4 < NCB) bucketbase[b0 + 4] = ex + v0 + v1 + v2 + v3;
    if (t == 0) bucketbase[NCB] = N_EDGES;
}

// ---------- Pass C: scatter into bucket-sorted ebuf (src:17 | localdst:7)
__global__ __launch_bounds__(256) void k_scatter2(const int* __restrict__ ei,
        const int* __restrict__ obase, const int* __restrict__ bucketbase,
        int* __restrict__ ebuf) {
    __shared__ int cur[NCB];
    int tile = blockIdx.x, t = threadIdx.x;
    for (int i = t; i < NCB; i += 256)
        cur[i] = bucketbase[i] + obase[tile * HPAD + i];
    __syncthreads();
    int base = tile * ETILE;
    int end = base + ETILE;
    for (int i = base + t; i < end; i += 256) {
        int sv = __builtin_nontemporal_load(ei + i);
        int d  = __builtin_nontemporal_load(ei + N_EDGES + i);
        int p = atomicAdd(&cur[d >> BSH], 1);
        ebuf[p] = sv | ((d & 127) << 17);
    }
}

// ---------- Pass D: per-bucket node-level CSR (128-node buckets), all in LDS
__global__ __launch_bounds__(256) void k_csr2(const int* __restrict__ ebuf,
        const int* __restrict__ bucketbase, int* __restrict__ rowptr,
        int* __restrict__ col) {
    __shared__ int cnt[128], cur[128];
    __shared__ int sa[128], sb[128];
    int b = blockIdx.x, t = threadIdx.x;
    int s = bucketbase[b], e = bucketbase[b + 1];
    if (t < 128) cnt[t] = 0;
    __syncthreads();
    for (int i = s + t; i < e; i += 256)
        atomicAdd(&cnt[__builtin_nontemporal_load(ebuf + i) >> 17], 1);
    __syncthreads();
    if (t < 128) sa[t] = cnt[t];
    __syncthreads();
    int* sp = sa; int* dp = sb;
    for (int off = 1; off < 128; off <<= 1) {
        if (t < 128) dp[t] = sp[t] + ((t >= off) ? sp[t - off] : 0);
        __syncthreads();
        int* tmp = sp; sp = dp; dp = tmp;
    }
    if (t < 128) {
        int rowbase = s + sp[t] - cnt[t];
        cur[t] = rowbase;
        rowptr[b * 128 + t] = rowbase;      // 625*128 == 80000 exactly
    }
    if (b == 0 && t == 128) rowptr[N_NODES] = N_EDGES;
    __syncthreads();
    for (int i = s + t; i < e; i += 256) {
        int pk = __builtin_nontemporal_load(ebuf + i);
        int p = atomicAdd(&cur[pk >> 17], 1);
        col[p] = pk & 0x1FFFF;
    }
}

// ---------- fused gather + MFMA linear: block = 64 nodes, wave = 16 nodes.
// Phase 1: gather (8 edge slots x 8 f16x8 chunks per lane), packed f16
// accumulate, rows parked in padded LDS. Phase 2: MFMA epilogue (f16).
// Wave-private LDS rows -> no barrier needed.  [round-4 proven]
__global__ __launch_bounds__(256) void k_gatherlin(
        const unsigned short* __restrict__ Xin,
        const int* __restrict__ rowptr, const int* __restrict__ col,
        const unsigned short* __restrict__ wf, const float* __restrict__ bias,
        unsigned short* __restrict__ out, int relu) {
    __shared__ uint4 sAgg[64][9];
    const half8f* Xq = (const half8f*)Xin;
    int t = threadIdx.x, w = t >> 6, lane = t & 63;
    int e = lane >> 3, c = lane & 7;
    int nb = blockIdx.x * 64 + w * 16;          // first node of this wave
    int rp = (lane <= 16) ? rowptr[nb + lane] : 0;
    for (int n = 0; n < 16; ++n) {
        int start = __shfl(rp, n), end = __shfl(rp, n + 1);
        half8f acc = {};
        int base = start;
        for (; base + 16 <= end; base += 16) {   // 2 16B loads in flight
            int i0 = __builtin_nontemporal_load(col + base + e);
            int i1 = __builtin_nontemporal_load(col + base + 8 + e);
            half8f v0 = Xq[(size_t)i0 * 8 + c];
            half8f v1 = Xq[(size_t)i1 * 8 + c];
            acc = acc + v0;
            acc = acc + v1;
        }
        for (; base + 8 <= end; base += 8) {
            int i0 = __builtin_nontemporal_load(col + base + e);
            acc = acc + Xq[(size_t)i0 * 8 + c];
        }
        int r = end - base;
        if (e < r) {
            int i0 = col[base + e];
            acc = acc + Xq[(size_t)i0 * 8 + c];
        }
#pragma unroll
        for (int off = 8; off < 64; off <<= 1) {
            uint4 au = __builtin_bit_cast(uint4, acc);
            uint4 bu;
            bu.x = __shfl_xor(au.x, off); bu.y = __shfl_xor(au.y, off);
            bu.z = __shfl_xor(au.z, off); bu.w = __shfl_xor(au.w, off);
            acc = acc + __builtin_bit_cast(half8f, bu);
        }
        if (e == 0) sAgg[w * 16 + n][c] = __builtin_bit_cast(uint4, acc);
    }
    // phase 2: out = act([agg|x] @ W + b)  (wave-private rows; lgkmcnt only)
    int quad = lane >> 4, l15 = lane & 15;
    int m = nb + l15;
    half8f a0 = *(const half8f*)&sAgg[w * 16 + l15][quad];
    half8f a1 = *(const half8f*)&sAgg[w * 16 + l15][4 + quad];
    const half8f* xr = (const half8f*)(Xin + (size_t)m * 64);
    half8f a2 = xr[quad];
    half8f a3 = xr[4 + quad];
    int orow = nb + quad * 4;
#pragma unroll
    for (int nt = 0; nt < 4; ++nt) {
        const half8f* wp = (const half8f*)(wf + ((size_t)(nt * 4) * 64 + lane) * 8);
        half8f b0 = wp[0];
        half8f b1 = wp[64];
        half8f b2 = wp[128];
        half8f b3 = wp[192];
        float4f acc = {0.f, 0.f, 0.f, 0.f};
        acc = __builtin_amdgcn_mfma_f32_16x16x32_f16(a0, b0, acc, 0, 0, 0);
        acc = __builtin_amdgcn_mfma_f32_16x16x32_f16(a1, b1, acc, 0, 0, 0);
        acc = __builtin_amdgcn_mfma_f32_16x16x32_f16(a2, b2, acc, 0, 0, 0);
        acc = __builtin_amdgcn_mfma_f32_16x16x32_f16(a3, b3, acc, 0, 0, 0);
        float bi = bias[nt * 16 + l15];
#pragma unroll
        for (int r2 = 0; r2 < 4; ++r2) {
            float v = acc[r2] + bi;
            if (relu) v = fmaxf(v, 0.f);
            out[(size_t)(orow + r2) * 64 + nt * 16 + l15] = f2h(v);
        }
    }
}

static __device__ __forceinline__ int lowerb(const int* a, int n, int key) {
    int lo = 0, hi = n;
    while (lo < hi) { int mid = (lo + hi) >> 1; if (a[mid] < key) lo = mid + 1; else hi = mid; }
    return lo;
}

// ---------- layer-3 collapse, stage 1: per-graph partial sums, 4 parts/graph
// [round-4 proven]
__global__ __launch_bounds__(256) void k_gsum(const unsigned short* __restrict__ h2,
        const int* __restrict__ rowptr, const int* __restrict__ col,
        const int* __restrict__ batch, float* __restrict__ S4) {
    __shared__ float red1[4][64];
    __shared__ float red2[4][64];
    const uint4* Xq = (const uint4*)h2;
    int g = blockIdx.x >> 2, part = blockIdx.x & 3;
    int t = threadIdx.x, w = t >> 6, lane = t & 63;
    int e = lane >> 3, c = lane & 7;
    int slot = w * 8 + e;                        // 32 edge slots
    int ns = lowerb(batch, N_NODES, g);
    int ne = lowerb(batch, N_NODES, g + 1);
    int a0 = ns + (int)(((long long)(ne - ns) * part) >> 2);
    int a1 = ns + (int)(((long long)(ne - ns) * (part + 1)) >> 2);
    int es = rowptr[a0], ee = rowptr[a1];
    float acc[8] = {0.f, 0.f, 0.f, 0.f, 0.f, 0.f, 0.f, 0.f};
    int idx = es + slot;
    for (; idx + 32 < ee; idx += 64) {           // 2 uint4 loads in flight
        int i0 = __builtin_nontemporal_load(col + idx);
        int i1 = __builtin_nontemporal_load(col + idx + 32);
        uint4 v0 = Xq[(size_t)i0 * 8 + c];
        uint4 v1 = Xq[(size_t)i1 * 8 + c];
        acc[0] += h_lo(v0.x) + h_lo(v1.x); acc[1] += h_hi(v0.x) + h_hi(v1.x);
        acc[2] += h_lo(v0.y) + h_lo(v1.y); acc[3] += h_hi(v0.y) + h_hi(v1.y);
        acc[4] += h_lo(v0.z) + h_lo(v1.z); acc[5] += h_hi(v0.z) + h_hi(v1.z);
        acc[6] += h_lo(v0.w) + h_lo(v1.w); acc[7] += h_hi(v0.w) + h_hi(v1.w);
    }
    if (idx < ee) {
        int i0 = col[idx];
        uint4 v0 = Xq[(size_t)i0 * 8 + c];
        acc[0] += h_lo(v0.x); acc[1] += h_hi(v0.x);
        acc[2] += h_lo(v0.y); acc[3] += h_hi(v0.y);
        acc[4] += h_lo(v0.z); acc[5] += h_hi(v0.z);
        acc[6] += h_lo(v0.w); acc[7] += h_hi(v0.w);
    }
    float acc2[8] = {0.f, 0.f, 0.f, 0.f, 0.f, 0.f, 0.f, 0.f};
    for (int i = a0 + slot; i < a1; i += 32) {   // node (root) sums
        uint4 v = Xq[(size_t)i * 8 + c];
        acc2[0] += h_lo(v.x); acc2[1] += h_hi(v.x);
        acc2[2] += h_lo(v.y); acc2[3] += h_hi(v.y);
        acc2[4] += h_lo(v.z); acc2[5] += h_hi(v.z);
        acc2[6] += h_lo(v.w); acc2[7] += h_hi(v.w);
    }
#pragma unroll
    for (int off = 8; off < 64; off <<= 1) {
#pragma unroll
        for (int j = 0; j < 8; ++j) {
            acc[j]  += __shfl_xor(acc[j],  off);
            acc2[j] += __shfl_xor(acc2[j], off);
        }
    }
    if (e == 0) {
#pragma unroll
        for (int j = 0; j < 8; ++j) {
            red1[w][c * 8 + j] = acc[j];
            red2[w][c * 8 + j] = acc2[j];
        }
    }
    __syncthreads();
    if (t < 64) {
        S4[(size_t)blockIdx.x * 128 + t] =
            red1[0][t] + red1[1][t] + red1[2][t] + red1[3][t];
    } else if (t < 128) {
        int d = t - 64;
        S4[(size_t)blockIdx.x * 128 + 64 + d] =
            red2[0][d] + red2[1][d] + red2[2][d] + red2[3][d];
    }
}

// ---------- layer-3 collapse, stage 2: pooled matmuls + head (all fp32)
__global__ __launch_bounds__(64) void k_head2(const float* __restrict__ S4,
        const int* __restrict__ batch,
        const float* __restrict__ wr3, const float* __restrict__ wo3,
        const float* __restrict__ b3,
        const float* __restrict__ wlin, const float* __restrict__ blin,
        float* __restrict__ out) {
    __shared__ float s1[64], s2[64], pl[64];
    int g = blockIdx.x, t = threadIdx.x;
    int ns = lowerb(batch, N_NODES, g);
    int ne = lowerb(batch, N_NODES, g + 1);
    float inv = 1.f / (float)((ne > ns) ? (ne - ns) : 1);
    const float* Sg = S4 + (size_t)g * 4 * 128;
    s1[t] = (Sg[t]       + Sg[128 + t]       + Sg[256 + t]       + Sg[384 + t]) * inv;
    s2[t] = (Sg[64 + t]  + Sg[192 + t]       + Sg[320 + t]       + Sg[448 + t]) * inv;
    __syncthreads();
    float acc = b3[t];
    for (int k = 0; k < 64; ++k)
        acc += s1[k] * wr3[t * 64 + k] + s2[k] * wo3[t * 64 + k];
    pl[t] = acc;
    __syncthreads();
    float myout = 0.f;
    for (int cls = 0; cls < NCLS; ++cls) {
        float vv = pl[t] * wlin[cls * 64 + t];
        for (int off = 32; off > 0; off >>= 1) vv += __shfl_xor(vv, off);
        if (t == cls) myout = vv + blin[cls];
    }
    if (t < NCLS) out[g * NCLS + t] = myout;
}

extern "C" void kernel_launch(void* const* d_in, const int* in_sizes, int n_in,
                              void* d_out, int out_size, void* d_ws, size_t ws_size,
                              hipStream_t stream) {
    const float* x     = (const float*)d_in[0];
    const int*   ei    = (const int*)d_in[1];
    const int*   batch = (const int*)d_in[2];
    const float* wr1 = (const float*)d_in[3];
    const float* b1  = (const float*)d_in[4];
    const float* wo1 = (const float*)d_in[5];
    const float* wr2 = (const float*)d_in[6];
    const float* b2  = (const float*)d_in[7];
    const float* wo2 = (const float*)d_in[8];
    const float* wr3 = (const float*)d_in[9];
    const float* b3  = (const float*)d_in[10];
    const float* wo3 = (const float*)d_in[11];
    const float* wlin = (const float*)d_in[12];
    const float* blin = (const float*)d_in[13];
    float* out = (float*)d_out;

    char* p = (char*)d_ws;
    auto alloc = [&](size_t bytes) { char* r = p; p += (bytes + 255) & ~(size_t)255; return r; };
    int*   rowptr  = (int*)alloc((N_NODES + 1) * sizeof(int));
    int*   hmat    = (int*)alloc((size_t)NTILE * HPAD * sizeof(int));
    int*   obase   = (int*)alloc((size_t)NTILE * HPAD * sizeof(int));
    int*   btot    = (int*)alloc(HPAD * sizeof(int));
    int*   bucketbase = (int*)alloc((NCB + 1) * sizeof(int));
    int*   ebuf    = (int*)alloc((size_t)N_EDGES * sizeof(int));
    int*   col     = (int*)alloc((size_t)N_EDGES * sizeof(int));
    unsigned short* wf  = (unsigned short*)alloc(2 * 8192 * sizeof(unsigned short));
    unsigned short* xbf = (unsigned short*)alloc((size_t)N_NODES * 64 * 2);
    unsigned short* hA  = (unsigned short*)alloc((size_t)N_NODES * 64 * 2);
    unsigned short* hB  = (unsigned short*)alloc((size_t)N_NODES * 64 * 2);
    float* S4      = (float*)alloc((size_t)N_GRAPHS * 4 * 128 * sizeof(float));

    // CSR build (deterministic two-level counting sort) + prep
    k_histprep<<<NTILE + 5064, 256, 0, stream>>>(ei, x, wr1, wo1, wr2, wo2,
                                                 hmat, xbf, wf);
    k_scanT   <<<NCB,   256, 0, stream>>>(hmat, obase, btot);
    k_scanB   <<<1,     256, 0, stream>>>(btot, bucketbase);
    k_scatter2<<<NTILE, 256, 0, stream>>>(ei, obase, bucketbase, ebuf);
    k_csr2    <<<NCB,   256, 0, stream>>>(ebuf, bucketbase, rowptr, col);

    // layers 1+2: fused gather+linear (f16 packed accumulate + MFMA)
    k_gatherlin<<<N_NODES / 64, 256, 0, stream>>>(xbf, rowptr, col, wf,        b1, hA, 1);
    k_gatherlin<<<N_NODES / 64, 256, 0, stream>>>(hA,  rowptr, col, wf + 8192, b2, hB, 1);

    // layer 3 + pool collapsed
    k_gsum <<<N_GRAPHS * 4, 256, 0, stream>>>(hB, rowptr, col, batch, S4);
    k_head2<<<N_GRAPHS,     64,  0, stream>>>(S4, batch, wr3, wo3, b3, wlin, blin, out);
}

// Round 10
// 238.327 us; speedup vs baseline: 1.5704x; 1.0656x over previous
//
#include <hip/hip_runtime.h>

#define N_NODES  80000
#define N_EDGES  1280000
#define N_GRAPHS 512
#define DIM      64
#define NCLS     10

#define ETILE    2048
#define NTILE    625      // N_EDGES / ETILE exactly
#define NCB      625      // 128-node buckets; 80000/128 = 625 exactly
#define BSH      7        // log2(128)
#define HPAD     640

typedef _Float16 half8f __attribute__((ext_vector_type(8)));  // 8 f16 (4 VGPRs)
typedef float float4f __attribute__((ext_vector_type(4)));    // 4 fp32 acc

static __device__ __forceinline__ unsigned short f2h(float f) {
    _Float16 h = (_Float16)f;                 // v_cvt_f16_f32, RNE
    return __builtin_bit_cast(unsigned short, h);
}
static __device__ __forceinline__ float h_lo(unsigned v) {
    return (float)__builtin_bit_cast(_Float16, (unsigned short)(v & 0xFFFF));
}
static __device__ __forceinline__ float h_hi(unsigned v) {
    return (float)__builtin_bit_cast(_Float16, (unsigned short)(v >> 16));
}

// ---------- Pass A (merged): blocks [0,NTILE) per-tile histogram over
// 128-node buckets; blocks [NTILE, NTILE+5000) cast x->f16; rest pack W1/W2.
__global__ __launch_bounds__(256) void k_histprep(const int* __restrict__ ei,
        const float* __restrict__ x,
        const float* __restrict__ wr1, const float* __restrict__ wo1,
        const float* __restrict__ wr2, const float* __restrict__ wo2,
        int* __restrict__ hmat, unsigned short* __restrict__ xb,
        unsigned short* __restrict__ wf) {
    __shared__ int hist[NCB];
    int bid = blockIdx.x, t = threadIdx.x;
    if (bid < NTILE) {
        int tile = bid;
        for (int i = t; i < NCB; i += 256) hist[i] = 0;
        __syncthreads();
        int base = tile * ETILE;
        int end = base + ETILE;
        for (int i = base + t; i < end; i += 256)
            atomicAdd(&hist[ei[N_EDGES + i] >> BSH], 1);
        __syncthreads();
        for (int i = t; i < NCB; i += 256) hmat[tile * HPAD + i] = hist[i];
        return;
    }
    int pb = bid - NTILE;
    if (pb < 5000) {
        int i = pb * 256 + t;                   // N_NODES*16 float4s
        float4 v = ((const float4*)x)[i];
        ushort4 o;
        o.x = f2h(v.x); o.y = f2h(v.y); o.z = f2h(v.z); o.w = f2h(v.w);
        ((ushort4*)xb)[i] = o;
    } else {
        int idx = (pb - 5000) * 256 + t;        // < 2*8192
        int j = idx & 7, lane = (idx >> 3) & 63;
        int ks = (idx >> 9) & 3, nt = (idx >> 11) & 3, l = idx >> 13;
        int k = ks * 32 + ((lane >> 4) & 3) * 8 + j;
        int n = nt * 16 + (lane & 15);
        const float* wr = (l == 0) ? wr1 : wr2;
        const float* wo = (l == 0) ? wo1 : wo2;
        float val = (k < 64) ? wr[n * 64 + k] : wo[n * 64 + (k - 64)];
        wf[idx] = f2h(val);
    }
}

// ---------- Pass B1: per-bucket exclusive scan across 625 tiles (3 elems/thr)
__global__ __launch_bounds__(256) void k_scanT(const int* __restrict__ hmat,
        int* __restrict__ obase, int* __restrict__ btot) {
    __shared__ int sa[256], sb[256];
    int b = blockIdx.x, t = threadIdx.x;
    int j0 = 3 * t;
    int l0 = (j0     < NTILE) ? hmat[(j0    ) * HPAD + b] : 0;
    int l1 = (j0 + 1 < NTILE) ? hmat[(j0 + 1) * HPAD + b] : 0;
    int l2 = (j0 + 2 < NTILE) ? hmat[(j0 + 2) * HPAD + b] : 0;
    int s = l0 + l1 + l2;
    sa[t] = s; __syncthreads();
    int* sp = sa; int* dp = sb;
    for (int off = 1; off < 256; off <<= 1) {
        dp[t] = sp[t] + ((t >= off) ? sp[t - off] : 0);
        __syncthreads();
        int* tmp = sp; sp = dp; dp = tmp;
    }
    int ex = sp[t] - s;
    if (j0     < NTILE) obase[(j0    ) * HPAD + b] = ex;
    if (j0 + 1 < NTILE) obase[(j0 + 1) * HPAD + b] = ex + l0;
    if (j0 + 2 < NTILE) obase[(j0 + 2) * HPAD + b] = ex + l0 + l1;
    if (t == 255) btot[b] = sp[255];
}

// ---------- Pass B2: one-block scan of 625 bucket totals -> bucket bases
__global__ __launch_bounds__(256) void k_scanB(const int* __restrict__ btot,
        int* __restrict__ bucketbase, int* __restrict__ rowptr) {
    __shared__ int sa[256], sb[256];
    int t = threadIdx.x;
    int b0 = t * 5;
    int v0 = (b0     < NCB) ? btot[b0]     : 0;
    int v1 = (b0 + 1 < NCB) ? btot[b0 + 1] : 0;
    int v2 = (b0 + 2 < NCB) ? btot[b0 + 2] : 0;
    int v3 = (b0 + 3 < NCB) ? btot[b0 + 3] : 0;
    int v4 = (b0 + 4 < NCB) ? btot[b0 + 4] : 0;
    int s = v0 + v1 + v2 + v3 + v4;
    sa[t] = s; __syncthreads();
    int* sp = sa; int* dp = sb;
    for (int off = 1; off < 256; off <<= 1) {
        dp[t] = sp[t] + ((t >= off) ? sp[t - off] : 0);
        __syncthreads();
        int* tmp = sp; sp = dp; dp = tmp;
    }
    int ex = sp[t] - s;
    if (b0     < NCB) bucketbase[b0]     = ex;
    if (b0 + 1 < NCB) bucketbase[b0 + 1] = ex + v0;
    if (b0 + 2 < NCB) bucketbase[b0 + 2] = ex + v0 + v1;
    if (b0 + 3 < NCB) bucketbase[b0 + 3] = ex + v0 + v1 + v2;
    if (b0 + 4 < NCB) bucketbase[b0 + 4] = ex + v0 + v1 + v2 + v3;
    if (t == 0) { bucketbase[NCB] = N_EDGES; rowptr[N_NODES] = N_EDGES; }
}

// ---------- Pass C: scatter into bucket-sorted ebuf (deterministic runs)
__global__ __launch_bounds__(256) void k_scatter2(const int* __restrict__ ei,
        const int* __restrict__ obase, const int* __restrict__ bucketbase,
        int* __restrict__ ebuf) {
    __shared__ int cur[NCB];
    int tile = blockIdx.x, t = threadIdx.x;
    for (int i = t; i < NCB; i += 256)
        cur[i] = bucketbase[i] + obase[tile * HPAD + i];
    __syncthreads();
    int base = tile * ETILE;
    int end = base + ETILE;
    for (int i = base + t; i < end; i += 256) {
        int sv = ei[i], d = ei[N_EDGES + i];
        int p = atomicAdd(&cur[d >> BSH], 1);
        ebuf[p] = sv | ((d & 127) << 17);   // src:17 bits, local dst:7 bits
    }
}

// ---------- Pass D: per-bucket node-level CSR (128-node buckets), all in LDS
__global__ __launch_bounds__(256) void k_csr2(const int* __restrict__ ebuf,
        const int* __restrict__ bucketbase, int* __restrict__ rowptr,
        int* __restrict__ col) {
    __shared__ int cnt[128], cur[128];
    __shared__ int sa[128], sb[128];
    int b = blockIdx.x, t = threadIdx.x;
    int s = bucketbase[b], e = bucketbase[b + 1];
    if (t < 128) cnt[t] = 0;
    __syncthreads();
    for (int i = s + t; i < e; i += 256) atomicAdd(&cnt[ebuf[i] >> 17], 1);
    __syncthreads();
    if (t < 128) sa[t] = cnt[t];
    __syncthreads();
    int* sp = sa; int* dp = sb;
    for (int off = 1; off < 128; off <<= 1) {
        if (t < 128) dp[t] = sp[t] + ((t >= off) ? sp[t - off] : 0);
        __syncthreads();
        int* tmp = sp; sp = dp; dp = tmp;
    }
    if (t < 128) {
        int rowbase = s + sp[t] - cnt[t];
        cur[t] = rowbase;
        rowptr[b * 128 + t] = rowbase;      // 625*128 == 80000 exactly
    }
    __syncthreads();
    for (int i = s + t; i < e; i += 256) {
        int pk = ebuf[i];
        int p = atomicAdd(&cur[pk >> 17], 1);
        col[p] = pk & 0x1FFFF;
    }
}

// ---------- fused gather + MFMA linear: block = 64 nodes, wave = 16 nodes.
__global__ __launch_bounds__(256) void k_gatherlin(
        const unsigned short* __restrict__ Xin,
        const int* __restrict__ rowptr, const int* __restrict__ col,
        const unsigned short* __restrict__ wf, const float* __restrict__ bias,
        unsigned short* __restrict__ out, int relu) {
    __shared__ uint4 sAgg[64][9];
    const half8f* Xq = (const half8f*)Xin;
    int t = threadIdx.x, w = t >> 6, lane = t & 63;
    int e = lane >> 3, c = lane & 7;
    int nb = blockIdx.x * 64 + w * 16;          // first node of this wave
    int rp = (lane <= 16) ? rowptr[nb + lane] : 0;
    for (int n = 0; n < 16; ++n) {
        int start = __shfl(rp, n), end = __shfl(rp, n + 1);
        half8f acc = {};
        int base = start;
        for (; base + 16 <= end; base += 16) {   // 2 16B loads in flight
            int i0 = col[base + e];
            int i1 = col[base + 8 + e];
            half8f v0 = Xq[(size_t)i0 * 8 + c];
            half8f v1 = Xq[(size_t)i1 * 8 + c];
            acc = acc + v0;
            acc = acc + v1;
        }
        for (; base + 8 <= end; base += 8) {
            int i0 = col[base + e];
            acc = acc + Xq[(size_t)i0 * 8 + c];
        }
        int r = end - base;
        if (e < r) {
            int i0 = col[base + e];
            acc = acc + Xq[(size_t)i0 * 8 + c];
        }
#pragma unroll
        for (int off = 8; off < 64; off <<= 1) {
            uint4 au = __builtin_bit_cast(uint4, acc);
            uint4 bu;
            bu.x = __shfl_xor(au.x, off); bu.y = __shfl_xor(au.y, off);
            bu.z = __shfl_xor(au.z, off); bu.w = __shfl_xor(au.w, off);
            acc = acc + __builtin_bit_cast(half8f, bu);
        }
        if (e == 0) sAgg[w * 16 + n][c] = __builtin_bit_cast(uint4, acc);
    }
    // phase 2: out = act([agg|x] @ W + b)  (wave-private rows; lgkmcnt only)
    int quad = lane >> 4, l15 = lane & 15;
    int m = nb + l15;
    half8f a0 = *(const half8f*)&sAgg[w * 16 + l15][quad];
    half8f a1 = *(const half8f*)&sAgg[w * 16 + l15][4 + quad];
    const half8f* xr = (const half8f*)(Xin + (size_t)m * 64);
    half8f a2 = xr[quad];
    half8f a3 = xr[4 + quad];
    int orow = nb + quad * 4;
#pragma unroll
    for (int nt = 0; nt < 4; ++nt) {
        const half8f* wp = (const half8f*)(wf + ((size_t)(nt * 4) * 64 + lane) * 8);
        half8f b0 = wp[0];
        half8f b1 = wp[64];
        half8f b2 = wp[128];
        half8f b3 = wp[192];
        float4f acc = {0.f, 0.f, 0.f, 0.f};
        acc = __builtin_amdgcn_mfma_f32_16x16x32_f16(a0, b0, acc, 0, 0, 0);
        acc = __builtin_amdgcn_mfma_f32_16x16x32_f16(a1, b1, acc, 0, 0, 0);
        acc = __builtin_amdgcn_mfma_f32_16x16x32_f16(a2, b2, acc, 0, 0, 0);
        acc = __builtin_amdgcn_mfma_f32_16x16x32_f16(a3, b3, acc, 0, 0, 0);
        float bi = bias[nt * 16 + l15];
#pragma unroll
        for (int r2 = 0; r2 < 4; ++r2) {
            float v = acc[r2] + bi;
            if (relu) v = fmaxf(v, 0.f);
            out[(size_t)(orow + r2) * 64 + nt * 16 + l15] = f2h(v);
        }
    }
}

static __device__ __forceinline__ int lowerb(const int* a, int n, int key) {
    int lo = 0, hi = n;
    while (lo < hi) { int mid = (lo + hi) >> 1; if (a[mid] < key) lo = mid + 1; else hi = mid; }
    return lo;
}

// ---------- layer-3 collapse, stage 1: per-graph partial sums, 4 parts/graph
__global__ __launch_bounds__(256) void k_gsum(const unsigned short* __restrict__ h2,
        const int* __restrict__ rowptr, const int* __restrict__ col,
        const int* __restrict__ batch, float* __restrict__ S4) {
    __shared__ float red1[4][64];
    __shared__ float red2[4][64];
    const uint4* Xq = (const uint4*)h2;
    int g = blockIdx.x >> 2, part = blockIdx.x & 3;
    int t = threadIdx.x, w = t >> 6, lane = t & 63;
    int e = lane >> 3, c = lane & 7;
    int slot = w * 8 + e;                        // 32 edge slots
    int ns = lowerb(batch, N_NODES, g);
    int ne = lowerb(batch, N_NODES, g + 1);
    int a0 = ns + (int)(((long long)(ne - ns) * part) >> 2);
    int a1 = ns + (int)(((long long)(ne - ns) * (part + 1)) >> 2);
    int es = rowptr[a0], ee = rowptr[a1];
    float acc[8] = {0.f, 0.f, 0.f, 0.f, 0.f, 0.f, 0.f, 0.f};
    int idx = es + slot;
    for (; idx + 32 < ee; idx += 64) {           // 2 uint4 loads in flight
        int i0 = col[idx];
        int i1 = col[idx + 32];
        uint4 v0 = Xq[(size_t)i0 * 8 + c];
        uint4 v1 = Xq[(size_t)i1 * 8 + c];
        acc[0] += h_lo(v0.x) + h_lo(v1.x); acc[1] += h_hi(v0.x) + h_hi(v1.x);
        acc[2] += h_lo(v0.y) + h_lo(v1.y); acc[3] += h_hi(v0.y) + h_hi(v1.y);
        acc[4] += h_lo(v0.z) + h_lo(v1.z); acc[5] += h_hi(v0.z) + h_hi(v1.z);
        acc[6] += h_lo(v0.w) + h_lo(v1.w); acc[7] += h_hi(v0.w) + h_hi(v1.w);
    }
    if (idx < ee) {
        int i0 = col[idx];
        uint4 v0 = Xq[(size_t)i0 * 8 + c];
        acc[0] += h_lo(v0.x); acc[1] += h_hi(v0.x);
        acc[2] += h_lo(v0.y); acc[3] += h_hi(v0.y);
        acc[4] += h_lo(v0.z); acc[5] += h_hi(v0.z);
        acc[6] += h_lo(v0.w); acc[7] += h_hi(v0.w);
    }
    float acc2[8] = {0.f, 0.f, 0.f, 0.f, 0.f, 0.f, 0.f, 0.f};
    for (int i = a0 + slot; i < a1; i += 32) {   // node (root) sums
        uint4 v = Xq[(size_t)i * 8 + c];
        acc2[0] += h_lo(v.x); acc2[1] += h_hi(v.x);
        acc2[2] += h_lo(v.y); acc2[3] += h_hi(v.y);
        acc2[4] += h_lo(v.z); acc2[5] += h_hi(v.z);
        acc2[6] += h_lo(v.w); acc2[7] += h_hi(v.w);
    }
#pragma unroll
    for (int off = 8; off < 64; off <<= 1) {
#pragma unroll
        for (int j = 0; j < 8; ++j) {
            acc[j]  += __shfl_xor(acc[j],  off);
            acc2[j] += __shfl_xor(acc2[j], off);
        }
    }
    if (e == 0) {
#pragma unroll
        for (int j = 0; j < 8; ++j) {
            red1[w][c * 8 + j] = acc[j];
            red2[w][c * 8 + j] = acc2[j];
        }
    }
    __syncthreads();
    if (t < 64) {
        S4[(size_t)blockIdx.x * 128 + t] =
            red1[0][t] + red1[1][t] + red1[2][t] + red1[3][t];
    } else if (t < 128) {
        int d = t - 64;
        S4[(size_t)blockIdx.x * 128 + 64 + d] =
            red2[0][d] + red2[1][d] + red2[2][d] + red2[3][d];
    }
}

// ---------- layer-3 collapse, stage 2: pooled matmuls + head (all fp32)
__global__ __launch_bounds__(64) void k_head2(const float* __restrict__ S4,
        const int* __restrict__ batch,
        const float* __restrict__ wr3, const float* __restrict__ wo3,
        const float* __restrict__ b3,
        const float* __restrict__ wlin, const float* __restrict__ blin,
        float* __restrict__ out) {
    __shared__ float s1[64], s2[64], pl[64];
    int g = blockIdx.x, t = threadIdx.x;
    int ns = lowerb(batch, N_NODES, g);
    int ne = lowerb(batch, N_NODES, g + 1);
    float inv = 1.f / (float)((ne > ns) ? (ne - ns) : 1);
    const float* Sg = S4 + (size_t)g * 4 * 128;
    s1[t] = (Sg[t]       + Sg[128 + t]       + Sg[256 + t]       + Sg[384 + t]) * inv;
    s2[t] = (Sg[64 + t]  + Sg[192 + t]       + Sg[320 + t]       + Sg[448 + t]) * inv;
    __syncthreads();
    float acc = b3[t];
    for (int k = 0; k < 64; ++k)
        acc += s1[k] * wr3[t * 64 + k] + s2[k] * wo3[t * 64 + k];
    pl[t] = acc;
    __syncthreads();
    float myout = 0.f;
    for (int cls = 0; cls < NCLS; ++cls) {
        float vv = pl[t] * wlin[cls * 64 + t];
        for (int off = 32; off > 0; off >>= 1) vv += __shfl_xor(vv, off);
        if (t == cls) myout = vv + blin[cls];
    }
    if (t < NCLS) out[g * NCLS + t] = myout;
}

extern "C" void kernel_launch(void* const* d_in, const int* in_sizes, int n_in,
                              void* d_out, int out_size, void* d_ws, size_t ws_size,
                              hipStream_t stream) {
    const float* x     = (const float*)d_in[0];
    const int*   ei    = (const int*)d_in[1];
    const int*   batch = (const int*)d_in[2];
    const float* wr1 = (const float*)d_in[3];
    const float* b1  = (const float*)d_in[4];
    const float* wo1 = (const float*)d_in[5];
    const float* wr2 = (const float*)d_in[6];
    const float* b2  = (const float*)d_in[7];
    const float* wo2 = (const float*)d_in[8];
    const float* wr3 = (const float*)d_in[9];
    const float* b3  = (const float*)d_in[10];
    const float* wo3 = (const float*)d_in[11];
    const float* wlin = (const float*)d_in[12];
    const float* blin = (const float*)d_in[13];
    float* out = (float*)d_out;

    char* p = (char*)d_ws;
    auto alloc = [&](size_t bytes) { char* r = p; p += (bytes + 255) & ~(size_t)255; return r; };
    int*   rowptr  = (int*)alloc((N_NODES + 1) * sizeof(int));
    int*   hmat    = (int*)alloc((size_t)NTILE * HPAD * sizeof(int));
    int*   obase   = (int*)alloc((size_t)NTILE * HPAD * sizeof(int));
    int*   btot    = (int*)alloc(HPAD * sizeof(int));
    int*   bucketbase = (int*)alloc((NCB + 1) * sizeof(int));
    int*   ebuf    = (int*)alloc((size_t)N_EDGES * sizeof(int));
    int*   col     = (int*)alloc((size_t)N_EDGES * sizeof(int));
    unsigned short* wf  = (unsigned short*)alloc(2 * 8192 * sizeof(unsigned short));
    unsigned short* xbf = (unsigned short*)alloc((size_t)N_NODES * 64 * 2);
    unsigned short* hA  = (unsigned short*)alloc((size_t)N_NODES * 64 * 2);
    unsigned short* hB  = (unsigned short*)alloc((size_t)N_NODES * 64 * 2);
    float* S4      = (float*)alloc((size_t)N_GRAPHS * 4 * 128 * sizeof(float));

    // CSR build (deterministic two-level counting sort) + prep
    k_histprep<<<NTILE + 5064, 256, 0, stream>>>(ei, x, wr1, wo1, wr2, wo2,
                                                 hmat, xbf, wf);
    k_scanT   <<<NCB,   256, 0, stream>>>(hmat, obase, btot);
    k_scanB   <<<1,     256, 0, stream>>>(btot, bucketbase, rowptr);
    k_scatter2<<<NTILE, 256, 0, stream>>>(ei, obase, bucketbase, ebuf);
    k_csr2    <<<NCB,   256, 0, stream>>>(ebuf, bucketbase, rowptr, col);

    // layers 1+2: fused gather+linear (f16 packed accumulate + MFMA)
    k_gatherlin<<<N_NODES / 64, 256, 0, stream>>>(xbf, rowptr, col, wf,        b1, hA, 1);
    k_gatherlin<<<N_NODES / 64, 256, 0, stream>>>(hA,  rowptr, col, wf + 8192, b2, hB, 1);

    // layer 3 + pool collapsed
    k_gsum <<<N_GRAPHS * 4, 256, 0, stream>>>(hB, rowptr, col, batch, S4);
    k_head2<<<N_GRAPHS,     64,  0, stream>>>(S4, batch, wr3, wo3, b3, wlin, blin, out);
}